// Round 2
// baseline (2459.217 us; speedup 1.0000x reference)
//
#include <hip/hip_runtime.h>
#include <stdint.h>

#define TLEN 2048
#define DDIM 2048
#define NHEAD 16
#define HDIM 128
#define BSZ 4

typedef short bf16x8 __attribute__((ext_vector_type(8)));
typedef float f32x4 __attribute__((ext_vector_type(4)));

__device__ __forceinline__ unsigned short f32_bf16(float f) {
  union { float f; unsigned int u; } v; v.f = f;
  unsigned int u = v.u;
  unsigned int r = (u + 0x7fffu + ((u >> 16) & 1u)) >> 16;
  return (unsigned short)r;
}

// ---------------- weight transpose + f32->bf16 convert ----------------
// in: [R][C] f32 (z-strided), out: [C][R] bf16 (z-strided)
__global__ __launch_bounds__(256) void transpose_bf16_kernel(
    const float* __restrict__ in, unsigned short* __restrict__ out,
    int R, int C, long in_z, long out_z) {
  __shared__ float tile[32][33];
  in += (long)blockIdx.z * in_z;
  out += (long)blockIdx.z * out_z;
  int c0 = blockIdx.x * 32, r0 = blockIdx.y * 32;
  int cr = threadIdx.x & 31, rr = threadIdx.x >> 5;  // rr in 0..7
#pragma unroll
  for (int i = 0; i < 4; ++i)
    tile[rr + i * 8][cr] = in[(long)(r0 + rr + i * 8) * C + c0 + cr];
  __syncthreads();
#pragma unroll
  for (int i = 0; i < 4; ++i)
    out[(long)(c0 + rr + i * 8) * R + r0 + cr] = f32_bf16(tile[cr][rr + i * 8]);
}

// ---------------- block reduction helper (sum, sumsq) ----------------
__device__ __forceinline__ void block_reduce2(float& s, float& q) {
#pragma unroll
  for (int off = 32; off >= 1; off >>= 1) {
    s += __shfl_xor(s, off);
    q += __shfl_xor(q, off);
  }
  __shared__ float rs[4], rq[4];
  int lane = threadIdx.x & 63, wid = threadIdx.x >> 6;
  if (lane == 0) { rs[wid] = s; rq[wid] = q; }
  __syncthreads();
  s = rs[0] + rs[1] + rs[2] + rs[3];
  q = rq[0] + rq[1] + rq[2] + rq[3];
}

// ---------------- LN1: x -> bf16 normalized ----------------
__global__ __launch_bounds__(256) void ln_kernel(
    const float* __restrict__ x, const float* __restrict__ g,
    const float* __restrict__ be, unsigned short* __restrict__ hb) {
  int row = blockIdx.x, tid = threadIdx.x;
  const float* xr = x + (long)row * DDIM;
  float4 v0 = *(const float4*)(xr + tid * 4);
  float4 v1 = *(const float4*)(xr + 1024 + tid * 4);
  float s = v0.x + v0.y + v0.z + v0.w + v1.x + v1.y + v1.z + v1.w;
  float q = v0.x * v0.x + v0.y * v0.y + v0.z * v0.z + v0.w * v0.w +
            v1.x * v1.x + v1.y * v1.y + v1.z * v1.z + v1.w * v1.w;
  block_reduce2(s, q);
  float mu = s * (1.0f / DDIM);
  float var = q * (1.0f / DDIM) - mu * mu;
  float rstd = rsqrtf(var + 1e-5f);
  float4 g0 = *(const float4*)(g + tid * 4);
  float4 g1v = *(const float4*)(g + 1024 + tid * 4);
  float4 b0 = *(const float4*)(be + tid * 4);
  float4 b1v = *(const float4*)(be + 1024 + tid * 4);
  ushort4 o0, o1;
  o0.x = f32_bf16((v0.x - mu) * rstd * g0.x + b0.x);
  o0.y = f32_bf16((v0.y - mu) * rstd * g0.y + b0.y);
  o0.z = f32_bf16((v0.z - mu) * rstd * g0.z + b0.z);
  o0.w = f32_bf16((v0.w - mu) * rstd * g0.w + b0.w);
  o1.x = f32_bf16((v1.x - mu) * rstd * g1v.x + b1v.x);
  o1.y = f32_bf16((v1.y - mu) * rstd * g1v.y + b1v.y);
  o1.z = f32_bf16((v1.z - mu) * rstd * g1v.z + b1v.z);
  o1.w = f32_bf16((v1.w - mu) * rstd * g1v.w + b1v.w);
  *(ushort4*)(hb + (long)row * DDIM + tid * 4) = o0;
  *(ushort4*)(hb + (long)row * DDIM + 1024 + tid * 4) = o1;
}

// ---------------- residual + LN2 (IN PLACE on xa==d_out): xa = x + xa; hb = LN(xa) ----------------
// NOTE: xa aliases the attention output AND the x2 destination -> no __restrict__ here.
__global__ __launch_bounds__(256) void resid_ln_kernel(
    const float* __restrict__ x, float* xa,
    const float* __restrict__ g, const float* __restrict__ be,
    unsigned short* __restrict__ hb) {
  int row = blockIdx.x, tid = threadIdx.x;
  const float* xr = x + (long)row * DDIM;
  float* ar = xa + (long)row * DDIM;
  float4 v0 = *(const float4*)(xr + tid * 4);
  float4 a0 = *(const float4*)(ar + tid * 4);
  float4 v1 = *(const float4*)(xr + 1024 + tid * 4);
  float4 a1 = *(const float4*)(ar + 1024 + tid * 4);
  v0.x += a0.x; v0.y += a0.y; v0.z += a0.z; v0.w += a0.w;
  v1.x += a1.x; v1.y += a1.y; v1.z += a1.z; v1.w += a1.w;
  *(float4*)(ar + tid * 4) = v0;
  *(float4*)(ar + 1024 + tid * 4) = v1;
  float s = v0.x + v0.y + v0.z + v0.w + v1.x + v1.y + v1.z + v1.w;
  float q = v0.x * v0.x + v0.y * v0.y + v0.z * v0.z + v0.w * v0.w +
            v1.x * v1.x + v1.y * v1.y + v1.z * v1.z + v1.w * v1.w;
  block_reduce2(s, q);
  float mu = s * (1.0f / DDIM);
  float var = q * (1.0f / DDIM) - mu * mu;
  float rstd = rsqrtf(var + 1e-5f);
  float4 g0 = *(const float4*)(g + tid * 4);
  float4 g1v = *(const float4*)(g + 1024 + tid * 4);
  float4 b0 = *(const float4*)(be + tid * 4);
  float4 b1v = *(const float4*)(be + 1024 + tid * 4);
  ushort4 o0, o1;
  o0.x = f32_bf16((v0.x - mu) * rstd * g0.x + b0.x);
  o0.y = f32_bf16((v0.y - mu) * rstd * g0.y + b0.y);
  o0.z = f32_bf16((v0.z - mu) * rstd * g0.z + b0.z);
  o0.w = f32_bf16((v0.w - mu) * rstd * g0.w + b0.w);
  o1.x = f32_bf16((v1.x - mu) * rstd * g1v.x + b1v.x);
  o1.y = f32_bf16((v1.y - mu) * rstd * g1v.y + b1v.y);
  o1.z = f32_bf16((v1.z - mu) * rstd * g1v.z + b1v.z);
  o1.w = f32_bf16((v1.w - mu) * rstd * g1v.w + b1v.w);
  *(ushort4*)(hb + (long)row * DDIM + tid * 4) = o0;
  *(ushort4*)(hb + (long)row * DDIM + 1024 + tid * 4) = o1;
}

// ---------------- MFMA GEMM core: C[128x128] = A[M,K] * Bt[N,K]^T ----------------
// A row-major [M][K] bf16; Bt row-major [N][K] bf16 (i.e. B transposed).
// 256 threads, 4 waves in 2x2; each wave 64x64 = 4x4 16x16x32 frags. BK=64.
__device__ __forceinline__ void gemm_core(const unsigned short* __restrict__ A,
                                          const unsigned short* __restrict__ Bt,
                                          int K, int m0, int n0,
                                          f32x4 acc[4][4]) {
  __shared__ unsigned short sA[128 * 72];  // +8 pad: break b128 phase conflicts
  __shared__ unsigned short sB[128 * 72];
  const int tid = threadIdx.x;
  const int lane = tid & 63, wid = tid >> 6;
  const int wm = (wid & 1) * 64, wn = (wid >> 1) * 64;
  const int lm = lane & 15, lq = lane >> 4;
#pragma unroll
  for (int mi = 0; mi < 4; ++mi)
#pragma unroll
    for (int ni = 0; ni < 4; ++ni)
      acc[mi][ni] = (f32x4){0.f, 0.f, 0.f, 0.f};
  const int nk = K >> 6;
  for (int kt = 0; kt < nk; ++kt) {
#pragma unroll
    for (int i = 0; i < 4; ++i) {
      int id = i * 256 + tid;        // 1024 chunks of 16B per 128x64 tile
      int row = id >> 3, kg = id & 7;
      uint4 va = *(const uint4*)(A + (long)(m0 + row) * K + kt * 64 + kg * 8);
      *(uint4*)(&sA[row * 72 + kg * 8]) = va;
      uint4 vb = *(const uint4*)(Bt + (long)(n0 + row) * K + kt * 64 + kg * 8);
      *(uint4*)(&sB[row * 72 + kg * 8]) = vb;
    }
    __syncthreads();
#pragma unroll
    for (int kc = 0; kc < 2; ++kc) {
      bf16x8 af[4], bfr[4];
#pragma unroll
      for (int mi = 0; mi < 4; ++mi)
        af[mi] = *(const bf16x8*)(&sA[(wm + mi * 16 + lm) * 72 + kc * 32 + lq * 8]);
#pragma unroll
      for (int ni = 0; ni < 4; ++ni)
        bfr[ni] = *(const bf16x8*)(&sB[(wn + ni * 16 + lm) * 72 + kc * 32 + lq * 8]);
#pragma unroll
      for (int mi = 0; mi < 4; ++mi)
#pragma unroll
        for (int ni = 0; ni < 4; ++ni)
          acc[mi][ni] = __builtin_amdgcn_mfma_f32_16x16x32_bf16(af[mi], bfr[ni], acc[mi][ni], 0, 0, 0);
    }
    __syncthreads();
  }
}

// ---------------- QKV projection GEMM (z: 0=Q,1=K,2=V-transposed) ----------------
__global__ __launch_bounds__(256) void gemm_qkv_kernel(
    const unsigned short* __restrict__ A, const unsigned short* __restrict__ WT,
    unsigned short* __restrict__ Qb, unsigned short* __restrict__ Kb,
    unsigned short* __restrict__ VTb,
    const float* __restrict__ bq, const float* __restrict__ bk,
    const float* __restrict__ bv) {
  int m0 = blockIdx.x * 128, n0 = blockIdx.y * 128;
  int z = blockIdx.z;
  const unsigned short* Bt = WT + (long)z * DDIM * DDIM;
  f32x4 acc[4][4];
  gemm_core(A, Bt, DDIM, m0, n0, acc);
  const float* bias = (z == 0) ? bq : (z == 1) ? bk : bv;
  int lane = threadIdx.x & 63, wid = threadIdx.x >> 6;
  int wm = (wid & 1) * 64, wn = (wid >> 1) * 64, lm = lane & 15, lq = lane >> 4;
  int h = n0 >> 7;  // BN=128 == HD: one head per n-tile
#pragma unroll
  for (int mi = 0; mi < 4; ++mi) {
    int rowb = m0 + wm + mi * 16 + lq * 4;
    int b = rowb >> 11, t0 = rowb & (TLEN - 1);
#pragma unroll
    for (int ni = 0; ni < 4; ++ni) {
      int col = n0 + wn + ni * 16 + lm;
      int e = col & (HDIM - 1);
      float bsv = bias[col];
      if (z < 2) {
        unsigned short* o = (z == 0) ? Qb : Kb;
        long base = ((long)(b * NHEAD + h) * TLEN + t0) * HDIM + e;
#pragma unroll
        for (int r = 0; r < 4; ++r)
          o[base + (long)r * HDIM] = f32_bf16(acc[mi][ni][r] + bsv);
      } else {
        long base = ((long)(b * NHEAD + h) * HDIM + e) * TLEN + t0;
        ushort4 pk;
        pk.x = f32_bf16(acc[mi][ni][0] + bsv);
        pk.y = f32_bf16(acc[mi][ni][1] + bsv);
        pk.z = f32_bf16(acc[mi][ni][2] + bsv);
        pk.w = f32_bf16(acc[mi][ni][3] + bsv);
        *(ushort4*)(VTb + base) = pk;  // contiguous along t
      }
    }
  }
}

// ---------------- FFN GEMMs. MODE 0: +bias,ReLU -> bf16. MODE 1: +bias+resid -> f32 ----------------
template <int MODE>
__global__ __launch_bounds__(256) void gemm_ffn_kernel(
    const unsigned short* __restrict__ A, const unsigned short* __restrict__ Bt,
    void* __restrict__ outv, const float* __restrict__ bias, int K, int N) {
  int m0 = blockIdx.x * 128, n0 = blockIdx.y * 128;
  f32x4 acc[4][4];
  gemm_core(A, Bt, K, m0, n0, acc);
  int lane = threadIdx.x & 63, wid = threadIdx.x >> 6;
  int wm = (wid & 1) * 64, wn = (wid >> 1) * 64, lm = lane & 15, lq = lane >> 4;
#pragma unroll
  for (int mi = 0; mi < 4; ++mi) {
    int rowb = m0 + wm + mi * 16 + lq * 4;
#pragma unroll
    for (int ni = 0; ni < 4; ++ni) {
      int col = n0 + wn + ni * 16 + lm;
      float bsv = bias[col];
#pragma unroll
      for (int r = 0; r < 4; ++r) {
        long idx = (long)(rowb + r) * N + col;
        float v = acc[mi][ni][r] + bsv;
        if (MODE == 0) {
          ((unsigned short*)outv)[idx] = f32_bf16(v > 0.f ? v : 0.f);
        } else {
          float* o = (float*)outv;
          o[idx] = o[idx] + v;  // residual x2 already there
        }
      }
    }
  }
}

// ---------------- Flash attention, MFMA, causal ----------------
// Grid (T/64, H, B). 4 waves; wave w owns q rows [q0+16w, q0+16w+16).
// Q,K: [B,H,T,HD] bf16 (natural layout == A/B frag layouts). V: [B,H,HD,T] bf16.
// Output written directly into d_out ([B,T,D] f32, head-concat columns).
__global__ __launch_bounds__(256) void attn_kernel(
    const unsigned short* __restrict__ Qb, const unsigned short* __restrict__ Kb,
    const unsigned short* __restrict__ VTb, float* __restrict__ Ob) {
  __shared__ unsigned short pl[4][16 * 40];  // per-wave P tile, padded stride 40
  const int tid = threadIdx.x, lane = tid & 63, wid = tid >> 6;
  const int lm = lane & 15, lq = lane >> 4;
  const int q0 = blockIdx.x * 64, h = blockIdx.y, b = blockIdx.z;
  const long bh = (long)(b * NHEAD + h);
  const unsigned short* qp = Qb + (bh * TLEN + q0 + wid * 16) * HDIM;
  const unsigned short* kp = Kb + bh * TLEN * HDIM;
  const unsigned short* vp = VTb + bh * HDIM * TLEN;
  bf16x8 qf[4];
#pragma unroll
  for (int c = 0; c < 4; ++c)
    qf[c] = *(const bf16x8*)(qp + lm * HDIM + c * 32 + lq * 8);
  f32x4 oacc[8];
#pragma unroll
  for (int c = 0; c < 8; ++c) oacc[c] = (f32x4){0.f, 0.f, 0.f, 0.f};
  float mr[4], lr[4];
#pragma unroll
  for (int r = 0; r < 4; ++r) { mr[r] = -3.0e38f; lr[r] = 0.f; }
  const float scale = 0.08838834764831845f;  // 1/sqrt(128)
  const float l2e = 1.4426950408889634f;
  const int qmaxw = q0 + wid * 16 + 15;  // per-wave causal bound (no WG barrier in loop)
  unsigned short* pw = &pl[wid][0];
  for (int kb = 0; kb <= qmaxw; kb += 32) {
    f32x4 s0 = (f32x4){0.f, 0.f, 0.f, 0.f}, s1 = (f32x4){0.f, 0.f, 0.f, 0.f};
    const unsigned short* kbp = kp + (long)kb * HDIM;
#pragma unroll
    for (int c = 0; c < 4; ++c) {
      bf16x8 k0 = *(const bf16x8*)(kbp + lm * HDIM + c * 32 + lq * 8);
      bf16x8 k1 = *(const bf16x8*)(kbp + (16 + lm) * HDIM + c * 32 + lq * 8);
      s0 = __builtin_amdgcn_mfma_f32_16x16x32_bf16(qf[c], k0, s0, 0, 0, 0);
      s1 = __builtin_amdgcn_mfma_f32_16x16x32_bf16(qf[c], k1, s1, 0, 0, 0);
    }
    float p0[4], p1[4], al[4];
#pragma unroll
    for (int r = 0; r < 4; ++r) {
      int qg = q0 + wid * 16 + lq * 4 + r;
      float v0 = s0[r] * scale, v1 = s1[r] * scale;
      if (kb + lm > qg) v0 = -3.0e38f;
      if (kb + 16 + lm > qg) v1 = -3.0e38f;
      float mx = fmaxf(v0, v1);
#pragma unroll
      for (int off = 8; off >= 1; off >>= 1) mx = fmaxf(mx, __shfl_xor(mx, off));
      float mn = fmaxf(mr[r], mx);
      float a = exp2f((mr[r] - mn) * l2e);
      float e0 = exp2f((v0 - mn) * l2e);
      float e1 = exp2f((v1 - mn) * l2e);
      float rs = e0 + e1;
#pragma unroll
      for (int off = 8; off >= 1; off >>= 1) rs += __shfl_xor(rs, off);
      lr[r] = lr[r] * a + rs;
      mr[r] = mn;
      al[r] = a; p0[r] = e0; p1[r] = e1;
    }
    // P (C-layout) -> LDS -> A-layout frags (m120 round-trip)
#pragma unroll
    for (int r = 0; r < 4; ++r) {
      pw[(lq * 4 + r) * 40 + lm] = f32_bf16(p0[r]);
      pw[(lq * 4 + r) * 40 + 16 + lm] = f32_bf16(p1[r]);
    }
#pragma unroll
    for (int c = 0; c < 8; ++c)
#pragma unroll
      for (int r = 0; r < 4; ++r) oacc[c][r] *= al[r];
    __asm__ volatile("s_waitcnt lgkmcnt(0)" ::: "memory");
    bf16x8 pf = *(const bf16x8*)(pw + lm * 40 + lq * 8);
    const unsigned short* vbp = vp + kb;
#pragma unroll
    for (int c = 0; c < 8; ++c) {
      bf16x8 vf = *(const bf16x8*)(vbp + (long)(c * 16 + lm) * TLEN + lq * 8);
      oacc[c] = __builtin_amdgcn_mfma_f32_16x16x32_bf16(pf, vf, oacc[c], 0, 0, 0);
    }
  }
  float inv[4];
#pragma unroll
  for (int r = 0; r < 4; ++r) inv[r] = 1.f / lr[r];
  float* ob = Ob + ((long)b * TLEN + q0 + wid * 16) * DDIM + (long)h * HDIM;
#pragma unroll
  for (int c = 0; c < 8; ++c)
#pragma unroll
    for (int r = 0; r < 4; ++r)
      ob[(long)(lq * 4 + r) * DDIM + c * 16 + lm] = oacc[c][r] * inv[r];
}

// ---------------- launch ----------------
extern "C" void kernel_launch(void* const* d_in, const int* in_sizes, int n_in,
                              void* d_out, int out_size, void* d_ws, size_t ws_size,
                              hipStream_t stream) {
  const float* x   = (const float*)d_in[0];
  const float* Wq  = (const float*)d_in[1];
  const float* bq  = (const float*)d_in[2];
  const float* Wk  = (const float*)d_in[3];
  const float* bk  = (const float*)d_in[4];
  const float* Wv  = (const float*)d_in[5];
  const float* bv  = (const float*)d_in[6];
  const float* W1  = (const float*)d_in[7];
  const float* b1  = (const float*)d_in[8];
  const float* W2  = (const float*)d_in[9];
  const float* b2  = (const float*)d_in[10];
  const float* g1  = (const float*)d_in[11];
  const float* be1 = (const float*)d_in[12];
  const float* g2  = (const float*)d_in[13];
  const float* be2 = (const float*)d_in[14];
  float* out = (float*)d_out;
  char* ws = (char*)d_ws;
  // ws layout, 159,383,552 bytes total (slot reuse via stream-sequential liveness):
  //   [0,  24M) wtqkv   (dead after gemm_qkv)
  //   [24M,56M) qb      (dead after attn)  -> ff1buf (FFN chunk buffer)
  //   [56M,88M) kbuf    (dead after attn)  -> wt1
  //   [88M,120M) vtb    (dead after attn)  -> wt2
  //   [120M,152M) hbf   (h1, then h2)
  unsigned short* wtqkv  = (unsigned short*)(ws + 0L);
  unsigned short* qb     = (unsigned short*)(ws + 25165824L);
  unsigned short* kbuf   = (unsigned short*)(ws + 58720256L);
  unsigned short* vtb    = (unsigned short*)(ws + 92274688L);
  unsigned short* hbf    = (unsigned short*)(ws + 125829120L);
  unsigned short* ff1buf = qb;    // overlay (qb dead after attn)
  unsigned short* wt1    = kbuf;  // overlay (kbuf dead after attn)
  unsigned short* wt2    = vtb;   // overlay (vtb dead after attn)

  dim3 blk(256);
  // QKV weight transpose+convert: per-head [D][HD] -> [HD][D]
  transpose_bf16_kernel<<<dim3(4, 64, 16), blk, 0, stream>>>(Wq, wtqkv, 2048, 128, 2048L * 128, 2048L * 128);
  transpose_bf16_kernel<<<dim3(4, 64, 16), blk, 0, stream>>>(Wk, wtqkv + 2048L * 2048, 2048, 128, 2048L * 128, 2048L * 128);
  transpose_bf16_kernel<<<dim3(4, 64, 16), blk, 0, stream>>>(Wv, wtqkv + 2L * 2048 * 2048, 2048, 128, 2048L * 128, 2048L * 128);

  ln_kernel<<<dim3(8192), blk, 0, stream>>>(x, g1, be1, hbf);
  gemm_qkv_kernel<<<dim3(64, 16, 3), blk, 0, stream>>>(hbf, wtqkv, qb, kbuf, vtb, bq, bk, bv);
  attn_kernel<<<dim3(32, 16, 4), blk, 0, stream>>>(qb, kbuf, vtb, out);

  // W1/W2 transposes AFTER attention, into dead kbuf/vtb slots
  transpose_bf16_kernel<<<dim3(256, 64, 1), blk, 0, stream>>>(W1, wt1, 2048, 8192, 0, 0);
  transpose_bf16_kernel<<<dim3(64, 256, 1), blk, 0, stream>>>(W2, wt2, 8192, 2048, 0, 0);

  // out = x + attn (in place), hbf = LN2(out)
  resid_ln_kernel<<<dim3(8192), blk, 0, stream>>>(x, out, g2, be2, hbf);

  // FFN chunked over M (4 chunks of 2048 rows); ff1buf = 2048x8192 bf16 in qb slot
  for (int c = 0; c < 4; ++c) {
    gemm_ffn_kernel<0><<<dim3(16, 64), blk, 0, stream>>>(
        hbf + (long)c * 2048 * DDIM, wt1, ff1buf, b1, DDIM, 4 * DDIM);
    gemm_ffn_kernel<1><<<dim3(16, 16), blk, 0, stream>>>(
        ff1buf, wt2, out + (long)c * 2048 * DDIM, b2, 4 * DDIM, DDIM);
  }
}

// Round 3
// 1983.264 us; speedup vs baseline: 1.2400x; 1.2400x over previous
//
#include <hip/hip_runtime.h>
#include <stdint.h>

#define TLEN 2048
#define DDIM 2048
#define NHEAD 16
#define HDIM 128
#define BSZ 4

typedef short bf16x8 __attribute__((ext_vector_type(8)));
typedef float f32x4 __attribute__((ext_vector_type(4)));

__device__ __forceinline__ unsigned short f32_bf16(float f) {
  union { float f; unsigned int u; } v; v.f = f;
  unsigned int u = v.u;
  unsigned int r = (u + 0x7fffu + ((u >> 16) & 1u)) >> 16;
  return (unsigned short)r;
}

// async 16B global->LDS (dest = wave-uniform base + lane*16)
__device__ __forceinline__ void async_cp16(const void* g, void* l) {
  __builtin_amdgcn_global_load_lds(
      (const __attribute__((address_space(1))) unsigned int*)g,
      (__attribute__((address_space(3))) unsigned int*)l, 16, 0, 0);
}

// ---------------- weight transpose + f32->bf16 convert ----------------
__global__ __launch_bounds__(256) void transpose_bf16_kernel(
    const float* __restrict__ in, unsigned short* __restrict__ out,
    int R, int C, long in_z, long out_z) {
  __shared__ float tile[32][33];
  in += (long)blockIdx.z * in_z;
  out += (long)blockIdx.z * out_z;
  int c0 = blockIdx.x * 32, r0 = blockIdx.y * 32;
  int cr = threadIdx.x & 31, rr = threadIdx.x >> 5;
#pragma unroll
  for (int i = 0; i < 4; ++i)
    tile[rr + i * 8][cr] = in[(long)(r0 + rr + i * 8) * C + c0 + cr];
  __syncthreads();
#pragma unroll
  for (int i = 0; i < 4; ++i)
    out[(long)(c0 + rr + i * 8) * R + r0 + cr] = f32_bf16(tile[cr][rr + i * 8]);
}

// ---------------- block reduction helper (sum, sumsq) ----------------
__device__ __forceinline__ void block_reduce2(float& s, float& q) {
#pragma unroll
  for (int off = 32; off >= 1; off >>= 1) {
    s += __shfl_xor(s, off);
    q += __shfl_xor(q, off);
  }
  __shared__ float rs[4], rq[4];
  int lane = threadIdx.x & 63, wid = threadIdx.x >> 6;
  if (lane == 0) { rs[wid] = s; rq[wid] = q; }
  __syncthreads();
  s = rs[0] + rs[1] + rs[2] + rs[3];
  q = rq[0] + rq[1] + rq[2] + rq[3];
}

// ---------------- LN1: x -> bf16 normalized ----------------
__global__ __launch_bounds__(256) void ln_kernel(
    const float* __restrict__ x, const float* __restrict__ g,
    const float* __restrict__ be, unsigned short* __restrict__ hb) {
  int row = blockIdx.x, tid = threadIdx.x;
  const float* xr = x + (long)row * DDIM;
  float4 v0 = *(const float4*)(xr + tid * 4);
  float4 v1 = *(const float4*)(xr + 1024 + tid * 4);
  float s = v0.x + v0.y + v0.z + v0.w + v1.x + v1.y + v1.z + v1.w;
  float q = v0.x * v0.x + v0.y * v0.y + v0.z * v0.z + v0.w * v0.w +
            v1.x * v1.x + v1.y * v1.y + v1.z * v1.z + v1.w * v1.w;
  block_reduce2(s, q);
  float mu = s * (1.0f / DDIM);
  float var = q * (1.0f / DDIM) - mu * mu;
  float rstd = rsqrtf(var + 1e-5f);
  float4 g0 = *(const float4*)(g + tid * 4);
  float4 g1v = *(const float4*)(g + 1024 + tid * 4);
  float4 b0 = *(const float4*)(be + tid * 4);
  float4 b1v = *(const float4*)(be + 1024 + tid * 4);
  ushort4 o0, o1;
  o0.x = f32_bf16((v0.x - mu) * rstd * g0.x + b0.x);
  o0.y = f32_bf16((v0.y - mu) * rstd * g0.y + b0.y);
  o0.z = f32_bf16((v0.z - mu) * rstd * g0.z + b0.z);
  o0.w = f32_bf16((v0.w - mu) * rstd * g0.w + b0.w);
  o1.x = f32_bf16((v1.x - mu) * rstd * g1v.x + b1v.x);
  o1.y = f32_bf16((v1.y - mu) * rstd * g1v.y + b1v.y);
  o1.z = f32_bf16((v1.z - mu) * rstd * g1v.z + b1v.z);
  o1.w = f32_bf16((v1.w - mu) * rstd * g1v.w + b1v.w);
  *(ushort4*)(hb + (long)row * DDIM + tid * 4) = o0;
  *(ushort4*)(hb + (long)row * DDIM + 1024 + tid * 4) = o1;
}

// ---------------- residual + LN2 (IN PLACE on xa==d_out) ----------------
__global__ __launch_bounds__(256) void resid_ln_kernel(
    const float* __restrict__ x, float* xa,
    const float* __restrict__ g, const float* __restrict__ be,
    unsigned short* __restrict__ hb) {
  int row = blockIdx.x, tid = threadIdx.x;
  const float* xr = x + (long)row * DDIM;
  float* ar = xa + (long)row * DDIM;
  float4 v0 = *(const float4*)(xr + tid * 4);
  float4 a0 = *(const float4*)(ar + tid * 4);
  float4 v1 = *(const float4*)(xr + 1024 + tid * 4);
  float4 a1 = *(const float4*)(ar + 1024 + tid * 4);
  v0.x += a0.x; v0.y += a0.y; v0.z += a0.z; v0.w += a0.w;
  v1.x += a1.x; v1.y += a1.y; v1.z += a1.z; v1.w += a1.w;
  *(float4*)(ar + tid * 4) = v0;
  *(float4*)(ar + 1024 + tid * 4) = v1;
  float s = v0.x + v0.y + v0.z + v0.w + v1.x + v1.y + v1.z + v1.w;
  float q = v0.x * v0.x + v0.y * v0.y + v0.z * v0.z + v0.w * v0.w +
            v1.x * v1.x + v1.y * v1.y + v1.z * v1.z + v1.w * v1.w;
  block_reduce2(s, q);
  float mu = s * (1.0f / DDIM);
  float var = q * (1.0f / DDIM) - mu * mu;
  float rstd = rsqrtf(var + 1e-5f);
  float4 g0 = *(const float4*)(g + tid * 4);
  float4 g1v = *(const float4*)(g + 1024 + tid * 4);
  float4 b0 = *(const float4*)(be + tid * 4);
  float4 b1v = *(const float4*)(be + 1024 + tid * 4);
  ushort4 o0, o1;
  o0.x = f32_bf16((v0.x - mu) * rstd * g0.x + b0.x);
  o0.y = f32_bf16((v0.y - mu) * rstd * g0.y + b0.y);
  o0.z = f32_bf16((v0.z - mu) * rstd * g0.z + b0.z);
  o0.w = f32_bf16((v0.w - mu) * rstd * g0.w + b0.w);
  o1.x = f32_bf16((v1.x - mu) * rstd * g1v.x + b1v.x);
  o1.y = f32_bf16((v1.y - mu) * rstd * g1v.y + b1v.y);
  o1.z = f32_bf16((v1.z - mu) * rstd * g1v.z + b1v.z);
  o1.w = f32_bf16((v1.w - mu) * rstd * g1v.w + b1v.w);
  *(ushort4*)(hb + (long)row * DDIM + tid * 4) = o0;
  *(ushort4*)(hb + (long)row * DDIM + 1024 + tid * 4) = o1;
}

// ---------------- MFMA GEMM core v2: global_load_lds + XOR swizzle ----------------
// LDS tiles 128x64 UNPADDED (global_load_lds forbids padding); bank conflicts
// broken by kg ^= (row&7) swizzle applied at stage (global src) and read.
__device__ __forceinline__ void gemm_core(const unsigned short* __restrict__ A,
                                          const unsigned short* __restrict__ Bt,
                                          int K, int m0, int n0,
                                          f32x4 acc[4][4]) {
  __shared__ unsigned short sA[128 * 64];
  __shared__ unsigned short sB[128 * 64];
  const int tid = threadIdx.x;
  const int lane = tid & 63, wid = tid >> 6;
  const int wm = (wid & 1) * 64, wn = (wid >> 1) * 64;
  const int lm = lane & 15, lq = lane >> 4;
#pragma unroll
  for (int mi = 0; mi < 4; ++mi)
#pragma unroll
    for (int ni = 0; ni < 4; ++ni)
      acc[mi][ni] = (f32x4){0.f, 0.f, 0.f, 0.f};
  const int rbase = wid * 32;        // wave stages rows [rbase, rbase+32)
  const int ri = lane >> 3;          // row within 8-row (1KB) chunk
  const int kgl = lane & 7;
  const int nk = K >> 6;
  for (int kt = 0; kt < nk; ++kt) {
    const unsigned short* Ak = A + (long)m0 * K + (long)kt * 64;
    const unsigned short* Bk = Bt + (long)n0 * K + (long)kt * 64;
#pragma unroll
    for (int ins = 0; ins < 4; ++ins) {
      int row = rbase + ins * 8 + ri;
      int kg = kgl ^ (row & 7);      // swizzled global source -> phys slot lane&7
      async_cp16(Ak + (long)row * K + kg * 8, &sA[(rbase + ins * 8) * 64]);
      async_cp16(Bk + (long)row * K + kg * 8, &sB[(rbase + ins * 8) * 64]);
    }
    __syncthreads();
#pragma unroll
    for (int kc = 0; kc < 2; ++kc) {
      bf16x8 af[4], bfr[4];
#pragma unroll
      for (int mi = 0; mi < 4; ++mi) {
        int row = wm + mi * 16 + lm;
        int kg = (kc * 4 + lq) ^ (row & 7);
        af[mi] = *(const bf16x8*)(&sA[row * 64 + kg * 8]);
      }
#pragma unroll
      for (int ni = 0; ni < 4; ++ni) {
        int row = wn + ni * 16 + lm;
        int kg = (kc * 4 + lq) ^ (row & 7);
        bfr[ni] = *(const bf16x8*)(&sB[row * 64 + kg * 8]);
      }
#pragma unroll
      for (int mi = 0; mi < 4; ++mi)
#pragma unroll
        for (int ni = 0; ni < 4; ++ni)
          acc[mi][ni] = __builtin_amdgcn_mfma_f32_16x16x32_bf16(af[mi], bfr[ni], acc[mi][ni], 0, 0, 0);
    }
    __syncthreads();
  }
}

// ---------------- QKV projection GEMM (z: 0=Q,1=K,2=V-transposed) ----------------
__global__ __launch_bounds__(256) void gemm_qkv_kernel(
    const unsigned short* __restrict__ A, const unsigned short* __restrict__ WT,
    unsigned short* __restrict__ Qb, unsigned short* __restrict__ Kb,
    unsigned short* __restrict__ VTb,
    const float* __restrict__ bq, const float* __restrict__ bk,
    const float* __restrict__ bv) {
  int m0 = blockIdx.x * 128, n0 = blockIdx.y * 128;
  int z = blockIdx.z;
  const unsigned short* Bt = WT + (long)z * DDIM * DDIM;
  f32x4 acc[4][4];
  gemm_core(A, Bt, DDIM, m0, n0, acc);
  const float* bias = (z == 0) ? bq : (z == 1) ? bk : bv;
  int lane = threadIdx.x & 63, wid = threadIdx.x >> 6;
  int wm = (wid & 1) * 64, wn = (wid >> 1) * 64, lm = lane & 15, lq = lane >> 4;
  int h = n0 >> 7;
#pragma unroll
  for (int mi = 0; mi < 4; ++mi) {
    int rowb = m0 + wm + mi * 16 + lq * 4;
    int b = rowb >> 11, t0 = rowb & (TLEN - 1);
#pragma unroll
    for (int ni = 0; ni < 4; ++ni) {
      int col = n0 + wn + ni * 16 + lm;
      int e = col & (HDIM - 1);
      float bsv = bias[col];
      if (z < 2) {
        unsigned short* o = (z == 0) ? Qb : Kb;
        long base = ((long)(b * NHEAD + h) * TLEN + t0) * HDIM + e;
#pragma unroll
        for (int r = 0; r < 4; ++r)
          o[base + (long)r * HDIM] = f32_bf16(acc[mi][ni][r] + bsv);
      } else {
        long base = ((long)(b * NHEAD + h) * HDIM + e) * TLEN + t0;
        ushort4 pk;
        pk.x = f32_bf16(acc[mi][ni][0] + bsv);
        pk.y = f32_bf16(acc[mi][ni][1] + bsv);
        pk.z = f32_bf16(acc[mi][ni][2] + bsv);
        pk.w = f32_bf16(acc[mi][ni][3] + bsv);
        *(ushort4*)(VTb + base) = pk;
      }
    }
  }
}

// ---------------- FFN GEMMs. MODE 0: +bias,ReLU -> bf16. MODE 1: +bias+resid -> f32 ----------------
template <int MODE>
__global__ __launch_bounds__(256) void gemm_ffn_kernel(
    const unsigned short* __restrict__ A, const unsigned short* __restrict__ Bt,
    void* __restrict__ outv, const float* __restrict__ bias, int K, int N) {
  int m0 = blockIdx.x * 128, n0 = blockIdx.y * 128;
  f32x4 acc[4][4];
  gemm_core(A, Bt, K, m0, n0, acc);
  int lane = threadIdx.x & 63, wid = threadIdx.x >> 6;
  int wm = (wid & 1) * 64, wn = (wid >> 1) * 64, lm = lane & 15, lq = lane >> 4;
#pragma unroll
  for (int mi = 0; mi < 4; ++mi) {
    int rowb = m0 + wm + mi * 16 + lq * 4;
#pragma unroll
    for (int ni = 0; ni < 4; ++ni) {
      int col = n0 + wn + ni * 16 + lm;
      float bsv = bias[col];
#pragma unroll
      for (int r = 0; r < 4; ++r) {
        long idx = (long)(rowb + r) * N + col;
        float v = acc[mi][ni][r] + bsv;
        if (MODE == 0) {
          ((unsigned short*)outv)[idx] = f32_bf16(v > 0.f ? v : 0.f);
        } else {
          float* o = (float*)outv;
          o[idx] = o[idx] + v;
        }
      }
    }
  }
}

// ---------------- Flash attention v2: 128 q-rows/block, K/V in LDS ----------------
// Grid (T/128, H, B), 4 waves; wave w owns q rows [q0+32w, q0+32w+32).
// Per iter (64 k-cols): coop-stage K[64x128]->sK(136), V^T[128x64]->sV(72);
// each wave: 32 QK MFMAs -> softmax -> P into per-wave overlay of sK -> 32 PV MFMAs.
__global__ __launch_bounds__(256) void attn_kernel(
    const unsigned short* __restrict__ Qb, const unsigned short* __restrict__ Kb,
    const unsigned short* __restrict__ VTb, float* __restrict__ Ob) {
  __shared__ unsigned short sK[64 * 136];   // 17408 B; P overlays after QK
  __shared__ unsigned short sV[128 * 72];   // 18432 B
  const int tid = threadIdx.x, lane = tid & 63, wid = tid >> 6;
  const int lm = lane & 15, lq = lane >> 4;
  const int q0 = blockIdx.x * 128, h = blockIdx.y, b = blockIdx.z;
  const long bh = (long)(b * NHEAD + h);
  const unsigned short* qp = Qb + (bh * TLEN + q0 + wid * 32) * HDIM;
  const unsigned short* kp = Kb + bh * TLEN * HDIM;
  const unsigned short* vp = VTb + bh * HDIM * TLEN;
  unsigned short* pw = sK + wid * (32 * 68);  // per-wave P tile 32x64, stride 68
  bf16x8 qf[2][4];
#pragma unroll
  for (int mi = 0; mi < 2; ++mi)
#pragma unroll
    for (int c = 0; c < 4; ++c)
      qf[mi][c] = *(const bf16x8*)(qp + (long)(mi * 16 + lm) * HDIM + c * 32 + lq * 8);
  f32x4 oacc[2][8];
#pragma unroll
  for (int mi = 0; mi < 2; ++mi)
#pragma unroll
    for (int c = 0; c < 8; ++c) oacc[mi][c] = (f32x4){0.f, 0.f, 0.f, 0.f};
  float mr[2][4], lr[2][4];
#pragma unroll
  for (int mi = 0; mi < 2; ++mi)
#pragma unroll
    for (int r = 0; r < 4; ++r) { mr[mi][r] = -3.0e38f; lr[mi][r] = 0.f; }
  const float scale = 0.08838834764831845f;  // 1/sqrt(128)
  const float l2e = 1.4426950408889634f;
  const int kend = q0 + 128;
  for (int kb = 0; kb < kend; kb += 64) {
    __syncthreads();  // prior-iter P/V reads done before restage
#pragma unroll
    for (int i = 0; i < 4; ++i) {
      int id = i * 256 + tid;
      int tr = id >> 4, kg = id & 15;
      uint4 kv = *(const uint4*)(kp + (long)(kb + tr) * HDIM + kg * 8);
      *(uint4*)(&sK[tr * 136 + kg * 8]) = kv;
      int ve = id >> 3, tg = id & 7;
      uint4 vv = *(const uint4*)(vp + (long)ve * TLEN + kb + tg * 8);
      *(uint4*)(&sV[ve * 72 + tg * 8]) = vv;
    }
    __syncthreads();
    // QK^T: S[32x64] per wave
    f32x4 s[2][4];
#pragma unroll
    for (int mi = 0; mi < 2; ++mi)
#pragma unroll
      for (int ni = 0; ni < 4; ++ni) s[mi][ni] = (f32x4){0.f, 0.f, 0.f, 0.f};
#pragma unroll
    for (int c = 0; c < 4; ++c) {
      bf16x8 bk[4];
#pragma unroll
      for (int ni = 0; ni < 4; ++ni)
        bk[ni] = *(const bf16x8*)(&sK[(ni * 16 + lm) * 136 + c * 32 + lq * 8]);
#pragma unroll
      for (int mi = 0; mi < 2; ++mi)
#pragma unroll
        for (int ni = 0; ni < 4; ++ni)
          s[mi][ni] = __builtin_amdgcn_mfma_f32_16x16x32_bf16(qf[mi][c], bk[ni], s[mi][ni], 0, 0, 0);
    }
    __syncthreads();  // all waves done reading sK before P overwrite
    // online softmax (rows: mi*16 + lq*4 + r; cols: kb + ni*16 + lm)
#pragma unroll
    for (int mi = 0; mi < 2; ++mi) {
#pragma unroll
      for (int r = 0; r < 4; ++r) {
        int qrow = q0 + wid * 32 + mi * 16 + lq * 4 + r;
        float v[4];
        float mx = -3.0e38f;
#pragma unroll
        for (int ni = 0; ni < 4; ++ni) {
          float t = s[mi][ni][r] * scale;
          if (kb + ni * 16 + lm > qrow) t = -3.0e38f;
          v[ni] = t;
          mx = fmaxf(mx, t);
        }
#pragma unroll
        for (int off = 8; off >= 1; off >>= 1) mx = fmaxf(mx, __shfl_xor(mx, off));
        float mn = fmaxf(mr[mi][r], mx);
        float a = exp2f((mr[mi][r] - mn) * l2e);
        float rs = 0.f;
        float p[4];
#pragma unroll
        for (int ni = 0; ni < 4; ++ni) {
          p[ni] = exp2f((v[ni] - mn) * l2e);
          rs += p[ni];
        }
#pragma unroll
        for (int off = 8; off >= 1; off >>= 1) rs += __shfl_xor(rs, off);
        lr[mi][r] = lr[mi][r] * a + rs;
        mr[mi][r] = mn;
        int prow = mi * 16 + lq * 4 + r;
#pragma unroll
        for (int ni = 0; ni < 4; ++ni)
          pw[prow * 68 + ni * 16 + lm] = f32_bf16(p[ni]);
#pragma unroll
        for (int c = 0; c < 8; ++c) oacc[mi][c][r] *= a;
      }
    }
    __asm__ volatile("s_waitcnt lgkmcnt(0)" ::: "memory");  // own-wave P visible
    // PV: O[32x128] += P[32x64] * V[64x128]
#pragma unroll
    for (int kc = 0; kc < 2; ++kc) {
      bf16x8 pf[2];
#pragma unroll
      for (int mi = 0; mi < 2; ++mi)
        pf[mi] = *(const bf16x8*)(&pw[(mi * 16 + lm) * 68 + kc * 32 + lq * 8]);
#pragma unroll
      for (int c = 0; c < 8; ++c) {
        bf16x8 vf = *(const bf16x8*)(&sV[(c * 16 + lm) * 72 + kc * 32 + lq * 8]);
#pragma unroll
        for (int mi = 0; mi < 2; ++mi)
          oacc[mi][c] = __builtin_amdgcn_mfma_f32_16x16x32_bf16(pf[mi], vf, oacc[mi][c], 0, 0, 0);
      }
    }
  }
  float* ob = Ob + ((long)b * TLEN + q0 + wid * 32) * DDIM + (long)h * HDIM;
#pragma unroll
  for (int mi = 0; mi < 2; ++mi) {
    float inv[4];
#pragma unroll
    for (int r = 0; r < 4; ++r) inv[r] = 1.f / lr[mi][r];
#pragma unroll
    for (int c = 0; c < 8; ++c)
#pragma unroll
      for (int r = 0; r < 4; ++r)
        ob[(long)(mi * 16 + lq * 4 + r) * DDIM + c * 16 + lm] = oacc[mi][c][r] * inv[r];
  }
}

// ---------------- launch ----------------
extern "C" void kernel_launch(void* const* d_in, const int* in_sizes, int n_in,
                              void* d_out, int out_size, void* d_ws, size_t ws_size,
                              hipStream_t stream) {
  const float* x   = (const float*)d_in[0];
  const float* Wq  = (const float*)d_in[1];
  const float* bq  = (const float*)d_in[2];
  const float* Wk  = (const float*)d_in[3];
  const float* bk  = (const float*)d_in[4];
  const float* Wv  = (const float*)d_in[5];
  const float* bv  = (const float*)d_in[6];
  const float* W1  = (const float*)d_in[7];
  const float* b1  = (const float*)d_in[8];
  const float* W2  = (const float*)d_in[9];
  const float* b2  = (const float*)d_in[10];
  const float* g1  = (const float*)d_in[11];
  const float* be1 = (const float*)d_in[12];
  const float* g2  = (const float*)d_in[13];
  const float* be2 = (const float*)d_in[14];
  float* out = (float*)d_out;
  char* ws = (char*)d_ws;
  // ws layout (152 MiB): [0,24M) wtqkv | [24M,56M) qb->ff1buf | [56M,88M) kbuf->wt1
  //                      | [88M,120M) vtb->wt2 | [120M,152M) hbf
  unsigned short* wtqkv  = (unsigned short*)(ws + 0L);
  unsigned short* qb     = (unsigned short*)(ws + 25165824L);
  unsigned short* kbuf   = (unsigned short*)(ws + 58720256L);
  unsigned short* vtb    = (unsigned short*)(ws + 92274688L);
  unsigned short* hbf    = (unsigned short*)(ws + 125829120L);
  unsigned short* ff1buf = qb;
  unsigned short* wt1    = kbuf;
  unsigned short* wt2    = vtb;

  dim3 blk(256);
  transpose_bf16_kernel<<<dim3(4, 64, 16), blk, 0, stream>>>(Wq, wtqkv, 2048, 128, 2048L * 128, 2048L * 128);
  transpose_bf16_kernel<<<dim3(4, 64, 16), blk, 0, stream>>>(Wk, wtqkv + 2048L * 2048, 2048, 128, 2048L * 128, 2048L * 128);
  transpose_bf16_kernel<<<dim3(4, 64, 16), blk, 0, stream>>>(Wv, wtqkv + 2L * 2048 * 2048, 2048, 128, 2048L * 128, 2048L * 128);

  ln_kernel<<<dim3(8192), blk, 0, stream>>>(x, g1, be1, hbf);
  gemm_qkv_kernel<<<dim3(64, 16, 3), blk, 0, stream>>>(hbf, wtqkv, qb, kbuf, vtb, bq, bk, bv);
  attn_kernel<<<dim3(16, 16, 4), blk, 0, stream>>>(qb, kbuf, vtb, out);

  transpose_bf16_kernel<<<dim3(256, 64, 1), blk, 0, stream>>>(W1, wt1, 2048, 8192, 0, 0);
  transpose_bf16_kernel<<<dim3(64, 256, 1), blk, 0, stream>>>(W2, wt2, 8192, 2048, 0, 0);

  resid_ln_kernel<<<dim3(8192), blk, 0, stream>>>(x, out, g2, be2, hbf);

  for (int c = 0; c < 4; ++c) {
    gemm_ffn_kernel<0><<<dim3(16, 64), blk, 0, stream>>>(
        hbf + (long)c * 2048 * DDIM, wt1, ff1buf, b1, DDIM, 4 * DDIM);
    gemm_ffn_kernel<1><<<dim3(16, 16), blk, 0, stream>>>(
        ff1buf, wt2, out + (long)c * 2048 * DDIM, b2, 4 * DDIM, DDIM);
  }
}